// Round 4
// baseline (10314.037 us; speedup 1.0000x reference)
//
#include <hip/hip_runtime.h>

#define TT 512
#define BB 64
#define EE 300
#define HH 1024
#define GG 4096
#define NSLOT 33   // h ring slots: large reuse distance => stale-L2 lines evicted

// Workspace layout (byte offsets computed in kernel_launch):
//   flags   256*4 B          per-block step flags
//   mirrors 8 lines x 128 B  region-min relay (word L of line r = min of region L)
//   cstate  1024*64*4 B      cell state [p][u][b]
//   hbuf    NSLOT x 256 KB, slot = t mod NSLOT, layout [kq][b][4]
//   mask    512*64*4 B       [t][b]
//   xz      tch*4096*64*4 B  [tl][g][b]

__device__ __forceinline__ float sigmf(float x) {
    return __fdividef(1.0f, 1.0f + __expf(-x));
}
__device__ __forceinline__ float tanhsf(float x) {
    float e = __expf(-2.0f * fabsf(x));
    float r = __fdividef(1.0f - e, 1.0f + e);
    return copysignf(r, x);
}

__global__ void mask_kernel(const int* __restrict__ seq, float* __restrict__ maskf) {
    int idx = blockIdx.x * 256 + threadIdx.x;   // covers 512*64
    int t = idx >> 6, b = idx & 63;
    maskf[idx] = (seq[b * TT + t] != 0) ? 1.0f : 0.0f;
}

// xz[tl][g][b] = sum_e emb[seq[b][t0+tl]][e] * wk[e][g] + bias[g]
__global__ __launch_bounds__(256, 4)
void xz_kernel(const float* __restrict__ emb, const float* __restrict__ wk,
               const float* __restrict__ bias, const int* __restrict__ seq,
               float* __restrict__ xz, int t0) {
    __shared__ int srow[128];
    __shared__ union {
        struct { float A[128 * 33]; float B[32 * 128]; } ab;
        float C[64 * 130];
    } u;
    const int tid = threadIdx.x;
    const int g0 = blockIdx.x << 7;
    const int by = blockIdx.y;
    if (tid < 128) {
        int b = tid & 63, t = t0 + (by << 1) + (tid >> 6);
        srow[tid] = seq[b * TT + t];
    }
    const int tx = tid & 15, ty = tid >> 4;
    float acc[8][8];
#pragma unroll
    for (int i = 0; i < 8; ++i)
#pragma unroll
        for (int j = 0; j < 8; ++j) acc[i][j] = 0.0f;
    __syncthreads();

    for (int kc = 0; kc < 10; ++kc) {
        const int e0 = kc << 5;
#pragma unroll
        for (int jj = 0; jj < 4; ++jj) {
            int idx = tid + (jj << 8);
            int kg = idx & 7, r = idx >> 3;
            int e = e0 + (kg << 2);
            float4 v = make_float4(0.f, 0.f, 0.f, 0.f);
            if (e <= 296) v = *(const float4*)(emb + srow[r] * EE + e);
            float* dst = u.ab.A + r * 33 + (kg << 2);
            dst[0] = v.x; dst[1] = v.y; dst[2] = v.z; dst[3] = v.w;
        }
#pragma unroll
        for (int jj = 0; jj < 4; ++jj) {
            int idx = tid + (jj << 8);
            int kk = idx >> 5, gg = idx & 31;
            int e = e0 + kk;
            float4 v = make_float4(0.f, 0.f, 0.f, 0.f);
            if (e < 300) v = *(const float4*)(wk + e * GG + g0 + (gg << 2));
            *(float4*)(u.ab.B + kk * 128 + (gg << 2)) = v;
        }
        __syncthreads();
        const float* Ab0 = u.ab.A + (4 * ty) * 33;
        const float* Ab1 = u.ab.A + (64 + 4 * ty) * 33;
#pragma unroll 2
        for (int k = 0; k < 32; ++k) {
            float av[8];
#pragma unroll
            for (int i = 0; i < 4; ++i) {
                av[i]     = Ab0[i * 33 + k];
                av[4 + i] = Ab1[i * 33 + k];
            }
            float4 b0 = *(const float4*)(u.ab.B + k * 128 + (tx << 2));
            float4 b1 = *(const float4*)(u.ab.B + k * 128 + 64 + (tx << 2));
            float bv[8] = {b0.x, b0.y, b0.z, b0.w, b1.x, b1.y, b1.z, b1.w};
#pragma unroll
            for (int i = 0; i < 8; ++i)
#pragma unroll
                for (int j = 0; j < 8; ++j) acc[i][j] = fmaf(av[i], bv[j], acc[i][j]);
        }
        __syncthreads();
    }

#pragma unroll
    for (int half = 0; half < 2; ++half) {
#pragma unroll
        for (int i = 0; i < 8; ++i) {
            int r = (i < 4) ? (4 * ty + i) : (64 + 4 * ty + (i - 4));
#pragma unroll
            for (int j = 0; j < 4; ++j)
                u.C[((tx << 2) + j) * 130 + r] = acc[i][(half << 2) + j];
        }
        __syncthreads();
#pragma unroll
        for (int it = 0; it < 32; ++it) {
            int idx = tid + (it << 8);
            int c = idx >> 7, rr = idx & 127;
            int g = g0 + (half << 6) + c;
            int tl = (by << 1) + (rr >> 6);
            int b = rr & 63;
            xz[(tl << 18) + (g << 6) + b] = u.C[c * 130 + rr] + bias[g];
        }
        __syncthreads();
    }
}

// Persistent LSTM: 256 WGs (1/CU via 98KB LDS) x 512 threads.
// Hierarchical sync (full-K reduction makes the step barrier global, so make
// propagation cheap): blocks publish flags[p]; 8 leader blocks relay their
// region's 32-flag min into 8 region-local mirror lines; each block's wave 0
// polls ONLY its region mirror line (32 sharers/line), then broadcasts via an
// LDS word that waves 1-7 spin on. Poll line-reads/round drop ~16x vs flat.
__global__ __launch_bounds__(512, 2)
void lstm_kernel(const float* __restrict__ xz, const float* __restrict__ rk,
                 const float* __restrict__ maskf, float* __restrict__ hbuf,
                 float* __restrict__ cstate, unsigned int* __restrict__ flags,
                 unsigned int* __restrict__ mirrors,
                 float* __restrict__ out, int t0, int nsteps) {
    __shared__ float Rs[16384];   // [k][16 cols], col c -> g = (c>>2)*1024 + 4p + (c&3)
    __shared__ float zb[8192];    // [wave][16][64] partial z
    __shared__ float cs[256];     // [u][b] cell state
    __shared__ float hsh[256];    // h swizzle [lane*4+w] for coalesced publish
    __shared__ unsigned int ready;  // LDS step broadcast
    const int tid = threadIdx.x;
    const int lane = tid & 63;
    const int w = tid >> 6;
    const int p = blockIdx.x;
    const int reg = p >> 5;                 // region = 32 blocks
    const bool isLeader = (p & 31) == 0;

    for (int i = tid; i < 16384; i += 512) {
        int k = i >> 4, c = i & 15;
        Rs[i] = rk[k * GG + ((c >> 2) << 10) + (p << 2) + (c & 3)];
    }
    if (tid < 256) cs[tid] = cstate[(p << 8) + tid];
    if (tid == 0) ready = (unsigned int)t0;
    int slot = t0 % NSLOT;
    int nslot = (slot + 1 == NSLOT) ? 0 : slot + 1;
    float hown = 0.0f;
    if (w < 4) hown = hbuf[(size_t)slot * 65536 + (p << 8) + (lane << 2) + w];
    const float4* Rs4 = (const float4*)Rs;
    __syncthreads();

    for (int t = t0; t < t0 + nsteps; ++t) {
        const float4* hp4 = (const float4*)(hbuf + (size_t)slot * 65536);
        float* hn = hbuf + (size_t)nslot * 65536;
        float m = maskf[(t << 6) + lane];      // issued before the wait
        float xzv[4] = {0.f, 0.f, 0.f, 0.f};
        if (w < 4) {
            const float* xzt = xz + ((size_t)(t - t0) << 18);
            int gb = (p << 2) + w;
#pragma unroll
            for (int gt = 0; gt < 4; ++gt)
                xzv[gt] = xzt[(((gt << 10) + gb) << 6) + lane];
        }
        // ---- wait: all producers must have published h^t ----
        if (t > t0) {
            unsigned int tgt = (unsigned int)t;
            if (w == 0) {
                const unsigned int* ml = mirrors + (reg << 5) + (lane & 7);
                while (!__all((int)(__hip_atomic_load(ml, __ATOMIC_RELAXED,
                                                      __HIP_MEMORY_SCOPE_AGENT) >= tgt)))
                    __builtin_amdgcn_s_sleep(2);
                __hip_atomic_store(&ready, tgt, __ATOMIC_RELAXED,
                                   __HIP_MEMORY_SCOPE_WORKGROUP);
            } else if (w == 1 && isLeader) {
                // relay: publish my region's 32-flag min into all 8 mirror lines
                unsigned int last = 0;
                for (;;) {
                    unsigned int f = __hip_atomic_load(flags + (reg << 5) + (lane & 31),
                                                       __ATOMIC_RELAXED,
                                                       __HIP_MEMORY_SCOPE_AGENT);
                    unsigned int mn = f;
#pragma unroll
                    for (int off = 1; off < 32; off <<= 1)
                        mn = min(mn, (unsigned int)__shfl_xor((int)mn, off));
                    mn = (unsigned int)__shfl((int)mn, 0);
                    if (mn > last) {
                        last = mn;
                        if (lane < 8)
                            __hip_atomic_store(mirrors + (lane << 5) + reg, mn,
                                               __ATOMIC_RELAXED, __HIP_MEMORY_SCOPE_AGENT);
                    }
                    if (__hip_atomic_load(&ready, __ATOMIC_RELAXED,
                                          __HIP_MEMORY_SCOPE_WORKGROUP) >= tgt) break;
                    __builtin_amdgcn_s_sleep(2);
                }
            } else {
                while (__hip_atomic_load(&ready, __ATOMIC_RELAXED,
                                         __HIP_MEMORY_SCOPE_WORKGROUP) < tgt)
                    __builtin_amdgcn_s_sleep(1);
            }
        }
        __builtin_amdgcn_sched_barrier(0);     // keep h loads after the wait
        float acc[16];
#pragma unroll
        for (int c = 0; c < 16; ++c) acc[c] = 0.0f;
        const int kq0 = w << 5;
#pragma unroll 4
        for (int kq = kq0; kq < kq0 + 32; ++kq) {
            float4 hv = hp4[(kq << 6) + lane];         // h[4kq..4kq+3][lane]
            const float4* rr = Rs4 + (kq << 4);
#define LSTM_STEPQ(q, comp) { \
            float4 r0 = rr[(q<<2)+0], r1 = rr[(q<<2)+1], r2 = rr[(q<<2)+2], r3 = rr[(q<<2)+3]; \
            acc[0]  = fmaf(comp, r0.x, acc[0]);  acc[1]  = fmaf(comp, r0.y, acc[1]);  \
            acc[2]  = fmaf(comp, r0.z, acc[2]);  acc[3]  = fmaf(comp, r0.w, acc[3]);  \
            acc[4]  = fmaf(comp, r1.x, acc[4]);  acc[5]  = fmaf(comp, r1.y, acc[5]);  \
            acc[6]  = fmaf(comp, r1.z, acc[6]);  acc[7]  = fmaf(comp, r1.w, acc[7]);  \
            acc[8]  = fmaf(comp, r2.x, acc[8]);  acc[9]  = fmaf(comp, r2.y, acc[9]);  \
            acc[10] = fmaf(comp, r2.z, acc[10]); acc[11] = fmaf(comp, r2.w, acc[11]); \
            acc[12] = fmaf(comp, r3.x, acc[12]); acc[13] = fmaf(comp, r3.y, acc[13]); \
            acc[14] = fmaf(comp, r3.z, acc[14]); acc[15] = fmaf(comp, r3.w, acc[15]); }
            LSTM_STEPQ(0, hv.x)
            LSTM_STEPQ(1, hv.y)
            LSTM_STEPQ(2, hv.z)
            LSTM_STEPQ(3, hv.w)
#undef LSTM_STEPQ
        }
#pragma unroll
        for (int c = 0; c < 16; ++c) zb[((w << 4) + c) * 64 + lane] = acc[c];
        __syncthreads();                               // (A) zb complete
        if (w < 4) {
            float z[4];
#pragma unroll
            for (int gt = 0; gt < 4; ++gt) {
                float s = xzv[gt];
                int c = (gt << 2) + w;
#pragma unroll
                for (int wp = 0; wp < 8; ++wp) s += zb[((wp << 4) + c) * 64 + lane];
                z[gt] = s;
            }
            float fi = sigmf(z[0]);
            float ff = sigmf(z[1]);
            float fg = tanhsf(z[2]);
            float fo = sigmf(z[3]);
            float co = cs[(w << 6) + lane];
            float cn = fmaf(ff, co, fi * fg);
            cn = fmaf(m, cn - co, co);                 // masked c update
            cs[(w << 6) + lane] = cn;
            float hc = fo * tanhsf(cn);
            hown = fmaf(m, hc - hown, hown);           // masked h update
            hsh[(lane << 2) + w] = hown;
        }
        __syncthreads();                               // (B) hsh ready, zb reads done
        if (tid < 256)                                 // coalesced agent-scope publish
            __hip_atomic_store(hn + (p << 8) + tid, hsh[tid],
                               __ATOMIC_RELAXED, __HIP_MEMORY_SCOPE_AGENT);
        __syncthreads();                               // (C) vmcnt(0): h visible
        if (tid == 0)
            __hip_atomic_store(flags + p, (unsigned int)(t + 1),
                               __ATOMIC_RELAXED, __HIP_MEMORY_SCOPE_AGENT);
        slot = nslot;
        nslot = (nslot + 1 == NSLOT) ? 0 : nslot + 1;
    }
    if (tid < 256) cstate[(p << 8) + tid] = cs[tid];
    if (t0 + nsteps == TT) {
        if (w < 4) zb[(w << 6) + lane] = hown;
        __syncthreads();
        if (tid < 64) {
            float4 v = make_float4(zb[tid], zb[64 + tid], zb[128 + tid], zb[192 + tid]);
            *(float4*)(out + tid * HH + (p << 2)) = v;
        }
    }
}

extern "C" void kernel_launch(void* const* d_in, const int* in_sizes, int n_in,
                              void* d_out, int out_size, void* d_ws, size_t ws_size,
                              hipStream_t stream) {
    const float* emb  = (const float*)d_in[0];
    const float* wk   = (const float*)d_in[1];
    const float* rk   = (const float*)d_in[2];
    const float* bias = (const float*)d_in[3];
    const int*   seq  = (const int*)d_in[4];
    float* out = (float*)d_out;
    char* ws = (char*)d_ws;

    // pick largest time-chunk that fits (NSLOT fixed)
    int tch = 128;
    size_t off_mirr, off_cstate, off_hbuf, off_mask, off_xz, total;
    for (;;) {
        off_mirr   = 1024;                                   // flags: 256*4
        off_cstate = off_mirr + 1024;                        // mirrors: 8*128B
        off_hbuf   = off_cstate + 262144;                    // cstate
        off_mask   = off_hbuf + (size_t)NSLOT * 262144;      // hbuf ring
        off_xz     = off_mask + 131072;                      // mask
        total      = off_xz + (size_t)tch * 1048576;         // xz chunk
        if (total <= ws_size || tch <= 4) break;
        tch >>= 1;
    }
    unsigned int* flags   = (unsigned int*)ws;
    unsigned int* mirrors = (unsigned int*)(ws + off_mirr);
    float* cstate = (float*)(ws + off_cstate);
    float* hbuf   = (float*)(ws + off_hbuf);
    float* maskf  = (float*)(ws + off_mask);
    float* xzbuf  = (float*)(ws + off_xz);

    // zero flags + mirrors + cstate + hbuf slot 0 (contiguous prefix)
    hipMemsetAsync(ws, 0, off_hbuf + 262144, stream);
    mask_kernel<<<128, 256, 0, stream>>>(seq, maskf);
    for (int t0 = 0; t0 < TT; t0 += tch) {
        xz_kernel<<<dim3(32, tch >> 1), 256, 0, stream>>>(emb, wk, bias, seq, xzbuf, t0);
        lstm_kernel<<<256, 512, 0, stream>>>(xzbuf, rk, maskf, hbuf, cstate, flags,
                                             mirrors, out, t0, tch);
    }
}

// Round 5
// 8854.865 us; speedup vs baseline: 1.1648x; 1.1648x over previous
//
#include <hip/hip_runtime.h>

#define TT 512
#define BB 64
#define EE 300
#define HH 1024
#define GG 4096
#define NSLOT 33   // h ring slots: large reuse distance => stale-L2 lines evicted

// Workspace layout:
//   flags   256*4 B   (@0, padded to 1 KB)   per-block step flags
//   cstate  1024*64*4 B                      cell state [p][u][b]
//   hbuf    NSLOT x 256 KB, slot = t mod NSLOT, layout [kq][b][4]
//   mask    512*64*4 B                       [t][b]
//   xT      512*300*64*4 B = 39.3 MB         x transposed [t][e][b]
// total ~48.4 MB

__device__ __forceinline__ float sigmf(float x) {
    return __fdividef(1.0f, 1.0f + __expf(-x));
}
__device__ __forceinline__ float tanhsf(float x) {
    float e = __expf(-2.0f * fabsf(x));
    float r = __fdividef(1.0f - e, 1.0f + e);
    return copysignf(r, x);
}

__global__ void mask_kernel(const int* __restrict__ seq, float* __restrict__ maskf) {
    int idx = blockIdx.x * 256 + threadIdx.x;   // covers 512*64
    int t = idx >> 6, b = idx & 63;
    maskf[idx] = (seq[b * TT + t] != 0) ? 1.0f : 0.0f;
}

// xT[t][e][b] = emb[seq[b][t]][e]  (block per t; LDS transpose, pad 305)
__global__ __launch_bounds__(256)
void xgather_kernel(const float* __restrict__ emb, const int* __restrict__ seq,
                    float* __restrict__ xT) {
    __shared__ float xrow[64 * 305];
    const int t = blockIdx.x, tid = threadIdx.x;
    const int r = tid >> 2, sub = tid & 3;
    const int row = seq[r * TT + t];
    for (int e = sub; e < EE; e += 4)
        xrow[r * 305 + e] = emb[row * EE + e];
    __syncthreads();
    float* dst = xT + (size_t)t * (EE * BB);
    for (int idx = tid; idx < EE * BB; idx += 256) {
        int e = idx >> 6, b = idx & 63;               // (17b+e)%32: conflict-free
        dst[idx] = xrow[b * 305 + e];
    }
}

// Persistent LSTM: 256 WGs (1/CU via ~128KB LDS) x 512 threads, ALL 512 steps
// in one dispatch. CU p owns gate-cols {g = gt*1024 + 4p + w}; R (64KB) and
// W (19.2KB) slices LDS-resident. Per step: compute zx(t+1)=x(t+1)·W during
// the wait bubble for h^t; per-wave flat producer flags (wave w waits only on
// blocks [32w,32w+32)); 8-deep h float4 prefetch ring hides MALL latency.
__global__ __launch_bounds__(512, 2)
void lstm_kernel(const float* __restrict__ xT, const float* __restrict__ rk,
                 const float* __restrict__ wk, const float* __restrict__ bias,
                 const float* __restrict__ maskf, float* __restrict__ hbuf,
                 float* __restrict__ cstate, unsigned int* __restrict__ flags,
                 float* __restrict__ out) {
    __shared__ float Rs[16384];    // [k][16 cols], col c -> g=(c>>2)*1024+4p+(c&3)
    __shared__ float Ws[4800];     // [e][16 cols], same col mapping
    __shared__ float zb[8192];     // [wave][16][64] partials (zx then recurrent)
    __shared__ float zxbuf[2048];  // [2][16][64] reduced zx + bias, double buffer
    __shared__ float cs[256];      // [u][b] cell state
    __shared__ float hsh[256];     // h swizzle for coalesced publish
    const int tid = threadIdx.x;
    const int lane = tid & 63;
    const int w = tid >> 6;
    const int p = blockIdx.x;

    for (int i = tid; i < 16384; i += 512) {
        int k = i >> 4, c = i & 15;
        Rs[i] = rk[k * GG + ((c >> 2) << 10) + (p << 2) + (c & 3)];
    }
    for (int i = tid; i < 4800; i += 512) {
        int e = i >> 4, c = i & 15;
        Ws[i] = wk[e * GG + ((c >> 2) << 10) + (p << 2) + (c & 3)];
    }
    if (tid < 256) cs[tid] = cstate[(p << 8) + tid];
    float bb[4];
    if (w < 4) {
#pragma unroll
        for (int gt = 0; gt < 4; ++gt)
            bb[gt] = bias[(gt << 10) + (p << 2) + w];
    }
    int slot = 0;
    int nslot = 1;
    float hown = 0.0f;   // h starts at 0 (hbuf slot 0 zeroed)
    const float4* Rs4 = (const float4*)Rs;
    const int fidx = (w << 5) + (lane & 31);   // this wave's producer flags
    const int e0 = w * 38;
    const int e1 = (e0 + 38 < EE) ? e0 + 38 : EE;
    __syncthreads();

    // ---- zx(t) into zxbuf[bi]: partials -> zb, reduce (+bias) by waves 0-3 ----
#define ZX_COMPUTE(tn, bi) {                                                   \
        if ((tn) < TT) {                                                       \
            const float* xt = xT + (size_t)(tn) * (EE * BB);                   \
            float zacc[16];                                                    \
            _Pragma("unroll") for (int c = 0; c < 16; ++c) zacc[c] = 0.0f;     \
            _Pragma("unroll 2") for (int e = e0; e < e1; ++e) {                \
                float xv = xt[(e << 6) + lane];                                \
                const float4* wr = (const float4*)(Ws + (e << 4));             \
                float4 q0 = wr[0], q1 = wr[1], q2 = wr[2], q3 = wr[3];         \
                zacc[0]  = fmaf(xv, q0.x, zacc[0]);  zacc[1]  = fmaf(xv, q0.y, zacc[1]);  \
                zacc[2]  = fmaf(xv, q0.z, zacc[2]);  zacc[3]  = fmaf(xv, q0.w, zacc[3]);  \
                zacc[4]  = fmaf(xv, q1.x, zacc[4]);  zacc[5]  = fmaf(xv, q1.y, zacc[5]);  \
                zacc[6]  = fmaf(xv, q1.z, zacc[6]);  zacc[7]  = fmaf(xv, q1.w, zacc[7]);  \
                zacc[8]  = fmaf(xv, q2.x, zacc[8]);  zacc[9]  = fmaf(xv, q2.y, zacc[9]);  \
                zacc[10] = fmaf(xv, q2.z, zacc[10]); zacc[11] = fmaf(xv, q2.w, zacc[11]); \
                zacc[12] = fmaf(xv, q3.x, zacc[12]); zacc[13] = fmaf(xv, q3.y, zacc[13]); \
                zacc[14] = fmaf(xv, q3.z, zacc[14]); zacc[15] = fmaf(xv, q3.w, zacc[15]); \
            }                                                                  \
            _Pragma("unroll") for (int c = 0; c < 16; ++c)                     \
                zb[((w << 4) + c) * 64 + lane] = zacc[c];                      \
        }                                                                      \
        __syncthreads();  /* S1 */                                             \
        if ((tn) < TT && w < 4) {                                              \
            _Pragma("unroll") for (int gt = 0; gt < 4; ++gt) {                 \
                int c = (gt << 2) + w;                                         \
                float s = bb[gt];                                              \
                _Pragma("unroll") for (int wp = 0; wp < 8; ++wp)               \
                    s += zb[((wp << 4) + c) * 64 + lane];                      \
                zxbuf[((bi) << 10) + (c << 6) + lane] = s;                     \
            }                                                                  \
        }                                                                      \
        __syncthreads();  /* S2 */                                             \
    }

    ZX_COMPUTE(0, 0)   // prologue: zx for step 0

    for (int t = 0; t < TT; ++t) {
        const float4* hp4 = (const float4*)(hbuf + (size_t)slot * 65536);
        float* hn = hbuf + (size_t)nslot * 65536;
        float m = maskf[(t << 6) + lane];

        ZX_COMPUTE(t + 1, (t + 1) & 1)     // fills the wait bubble below

        // per-wave wait: h^t from my 32 producers must be published
        if (t > 0) {
            unsigned int tgt = (unsigned int)t;
            while (!__all((int)(__hip_atomic_load(flags + fidx, __ATOMIC_RELAXED,
                                                  __HIP_MEMORY_SCOPE_AGENT) >= tgt)))
                __builtin_amdgcn_s_sleep(1);
        }
        __builtin_amdgcn_sched_barrier(0);  // keep h loads after the wait

        float acc[16];
#pragma unroll
        for (int c = 0; c < 16; ++c) acc[c] = 0.0f;
        const int kq0 = w << 5;
        float4 hv[8];
#pragma unroll
        for (int i = 0; i < 8; ++i) hv[i] = hp4[((kq0 + i) << 6) + lane];
        for (int g8 = 0; g8 < 4; ++g8) {   // 8-deep prefetch ring, const indices
#pragma unroll
            for (int j = 0; j < 8; ++j) {
                float4 cur = hv[j];
                int kq = (g8 << 3) + j;
                if (g8 < 3) hv[j] = hp4[((kq0 + kq + 8) << 6) + lane];
                const float4* rr = Rs4 + ((kq0 + kq) << 4);
#define LSTM_STEPQ(q, comp) { \
                float4 r0 = rr[(q<<2)+0], r1 = rr[(q<<2)+1], r2 = rr[(q<<2)+2], r3 = rr[(q<<2)+3]; \
                acc[0]  = fmaf(comp, r0.x, acc[0]);  acc[1]  = fmaf(comp, r0.y, acc[1]);  \
                acc[2]  = fmaf(comp, r0.z, acc[2]);  acc[3]  = fmaf(comp, r0.w, acc[3]);  \
                acc[4]  = fmaf(comp, r1.x, acc[4]);  acc[5]  = fmaf(comp, r1.y, acc[5]);  \
                acc[6]  = fmaf(comp, r1.z, acc[6]);  acc[7]  = fmaf(comp, r1.w, acc[7]);  \
                acc[8]  = fmaf(comp, r2.x, acc[8]);  acc[9]  = fmaf(comp, r2.y, acc[9]);  \
                acc[10] = fmaf(comp, r2.z, acc[10]); acc[11] = fmaf(comp, r2.w, acc[11]); \
                acc[12] = fmaf(comp, r3.x, acc[12]); acc[13] = fmaf(comp, r3.y, acc[13]); \
                acc[14] = fmaf(comp, r3.z, acc[14]); acc[15] = fmaf(comp, r3.w, acc[15]); }
                LSTM_STEPQ(0, cur.x)
                LSTM_STEPQ(1, cur.y)
                LSTM_STEPQ(2, cur.z)
                LSTM_STEPQ(3, cur.w)
#undef LSTM_STEPQ
            }
        }
#pragma unroll
        for (int c = 0; c < 16; ++c) zb[((w << 4) + c) * 64 + lane] = acc[c];
        __syncthreads();                               // S3: recurrent partials done
        if (w < 4) {
            float z[4];
#pragma unroll
            for (int gt = 0; gt < 4; ++gt) {
                int c = (gt << 2) + w;
                float s = zxbuf[((t & 1) << 10) + (c << 6) + lane];
#pragma unroll
                for (int wp = 0; wp < 8; ++wp) s += zb[((wp << 4) + c) * 64 + lane];
                z[gt] = s;
            }
            float fi = sigmf(z[0]);
            float ff = sigmf(z[1]);
            float fg = tanhsf(z[2]);
            float fo = sigmf(z[3]);
            float co = cs[(w << 6) + lane];
            float cn = fmaf(ff, co, fi * fg);
            cn = fmaf(m, cn - co, co);                 // masked c update
            cs[(w << 6) + lane] = cn;
            float hc = fo * tanhsf(cn);
            hown = fmaf(m, hc - hown, hown);           // masked h update
            hsh[(lane << 2) + w] = hown;
        }
        __syncthreads();                               // S4: hsh ready
        if (tid < 256)                                 // coalesced agent-scope publish
            __hip_atomic_store(hn + (p << 8) + tid, hsh[tid],
                               __ATOMIC_RELAXED, __HIP_MEMORY_SCOPE_AGENT);
        __syncthreads();                               // S5: vmcnt(0), h visible
        if (tid == 0)
            __hip_atomic_store(flags + p, (unsigned int)(t + 1),
                               __ATOMIC_RELAXED, __HIP_MEMORY_SCOPE_AGENT);
        slot = nslot;
        nslot = (nslot + 1 == NSLOT) ? 0 : nslot + 1;
    }
#undef ZX_COMPUTE
    if (tid < 256) cstate[(p << 8) + tid] = cs[tid];
    if (w < 4) zb[(w << 6) + lane] = hown;
    __syncthreads();
    if (tid < 64) {
        float4 v = make_float4(zb[tid], zb[64 + tid], zb[128 + tid], zb[192 + tid]);
        *(float4*)(out + tid * HH + (p << 2)) = v;
    }
}

extern "C" void kernel_launch(void* const* d_in, const int* in_sizes, int n_in,
                              void* d_out, int out_size, void* d_ws, size_t ws_size,
                              hipStream_t stream) {
    const float* emb  = (const float*)d_in[0];
    const float* wk   = (const float*)d_in[1];
    const float* rk   = (const float*)d_in[2];
    const float* bias = (const float*)d_in[3];
    const int*   seq  = (const int*)d_in[4];
    float* out = (float*)d_out;
    char* ws = (char*)d_ws;

    const size_t off_cstate = 1024;
    const size_t off_hbuf   = off_cstate + 262144;
    const size_t off_mask   = off_hbuf + (size_t)NSLOT * 262144;
    const size_t off_xT     = off_mask + 131072;
    unsigned int* flags = (unsigned int*)ws;
    float* cstate = (float*)(ws + off_cstate);
    float* hbuf   = (float*)(ws + off_hbuf);
    float* maskf  = (float*)(ws + off_mask);
    float* xT     = (float*)(ws + off_xT);

    // zero flags + cstate + hbuf slot 0 (contiguous prefix)
    hipMemsetAsync(ws, 0, off_hbuf + 262144, stream);
    mask_kernel<<<128, 256, 0, stream>>>(seq, maskf);
    xgather_kernel<<<TT, 256, 0, stream>>>(emb, seq, xT);
    lstm_kernel<<<256, 512, 0, stream>>>(xT, rk, wk, bias, maskf, hbuf, cstate,
                                         flags, out);
}